// Round 17
// baseline (308.136 us; speedup 1.0000x reference)
//
#include <hip/hip_runtime.h>
#include <math.h>

// BRIMCell forward — bf16 MFMA front GEMMs; fp8(e4m3) v2/ctx stream.
// R17: gemm_out_fp8 retiled to BM=256 x TN=256 (CB=1, CTX read ONCE),
// 1024-thread / 16-wave blocks, 4x4 wave grid, acc[4][4] per wave.

#define B_TOT 8192
#define NU 8
#define HH 256

typedef __attribute__((ext_vector_type(8))) short bf16x8;
typedef __attribute__((ext_vector_type(4))) float f32x4;
typedef unsigned long long u64;

__device__ __forceinline__ float sigm(float x){ return 1.0f/(1.0f+expf(-x)); }

__device__ __forceinline__ unsigned short f2bf(float f){
    union { float f; unsigned int u; } v; v.f = f;
    unsigned int r = v.u + 0x7fffu + ((v.u >> 16) & 1u);
    return (unsigned short)(r >> 16);
}
__device__ __forceinline__ float bf2f(unsigned short h){
    union { unsigned int u; float f; } v; v.u = ((unsigned int)h) << 16;
    return v.f;
}
__device__ __forceinline__ unsigned char f2fp8(float v){
    int p = __builtin_amdgcn_cvt_pk_fp8_f32(v, v, 0, false);
    return (unsigned char)(p & 0xff);
}

// ---------- fused weight packing ----------
#define TG (8*1024*288)
#define TQ (8*1152*256)
#define TO (8*256*1024)
#define TK (48*256)
#define TL (8*16*256)
__global__ void pack_all(const float* __restrict__ Wh2h, const float* __restrict__ Wx2h,
                         const float* __restrict__ Wq_,  const float* __restrict__ Wk_,
                         const float* __restrict__ Wv_,  const float* __restrict__ Wout,
                         const float* __restrict__ Wkey, const float* __restrict__ Wval,
                         const float* __restrict__ Wq,
                         unsigned short* __restrict__ Wg, unsigned short* __restrict__ Wqkv,
                         unsigned char* __restrict__ Wo8, unsigned short* __restrict__ Wkv,
                         unsigned short* __restrict__ Wqt)
{
    long long gidx = (long long)blockIdx.x*256 + threadIdx.x;
    if (gidx < TG) {
        int idx = (int)gidx;
        int k  = idx % 288;
        int pc = (idx / 288) % 1024;
        int n  = idx / (288*1024);
        int cb = pc >> 7, r = pc & 127;
        int g = r >> 5, ol = r & 31;
        int o = cb*32 + ol;
        float v = 0.f;
        if (g == 0)      v = (k < 256) ? Wh2h[((size_t)n*256 + k)*768 + o]
                                       : Wx2h[((size_t)n*32 + (k-256))*768 + o];
        else if (g == 1) v = (k < 256) ? Wh2h[((size_t)n*256 + k)*768 + 256 + o]
                                       : Wx2h[((size_t)n*32 + (k-256))*768 + 256 + o];
        else if (g == 2) v = (k >= 256) ? Wx2h[((size_t)n*32 + (k-256))*768 + 512 + o] : 0.f;
        else             v = (k < 256) ? Wh2h[((size_t)n*256 + k)*768 + 512 + o] : 0.f;
        Wg[idx] = f2bf(v);
        return;
    }
    gidx -= TG;
    if (gidx < TQ) {
        int idx = (int)gidx;
        int k = idx % 256;
        int c = (idx / 256) % 1152;
        int n = idx / (256*1152);
        float v = 0.f;
        if (c < 32)        v = Wq_[((size_t)n*256+k)*32 + c];
        else if (c < 64)   v = Wk_[((size_t)n*256+k)*32 + (c-32)];
        else if (c < 1088) v = Wv_[((size_t)n*256+k)*1024 + (c-64)];
        Wqkv[idx] = f2bf(v);
        return;
    }
    gidx -= TQ;
    if (gidx < TO) {                 // Wout -> fp8, [n][c(256)][k(1024)]
        int idx = (int)gidx;
        int k = idx % 1024;
        int c = (idx / 1024) % 256;
        int n = idx / (1024*256);
        Wo8[idx] = f2fp8(Wout[((size_t)n*1024 + k)*256 + c]);
        return;
    }
    gidx -= TO;
    if (gidx < TK) {
        int idx = (int)gidx;
        int k = idx & 255, c = idx >> 8;
        float v = (c < 16) ? Wkey[k*16 + c] : Wval[k*32 + (c-16)];
        Wkv[(size_t)c*256 + k] = f2bf(v);
        return;
    }
    gidx -= TK;
    if (gidx < TL) {
        int idx = (int)gidx;
        int k = idx & 255, c = (idx >> 8) & 15, n = idx >> 12;
        Wqt[((size_t)n*16 + c)*256 + k] = f2bf(Wq[((size_t)n*256 + k)*16 + c]);
    }
}

// ---------- small MFMA GEMM for stage-A precursors ----------
template<int SRC>
__global__ __launch_bounds__(256) void small_gemm(
    const float* __restrict__ A0, const float* __restrict__ A1,
    const unsigned short* __restrict__ Wp, float* __restrict__ C,
    unsigned short* __restrict__ hsb)
{
    constexpr int M    = (SRC == 0) ? 48 : 16;
    constexpr int NJ   = M/16;
    constexpr int AREG = 128*16;
    constexpr int WREG = M*16;
    int row0 = blockIdx.x * 128;
    int n = (SRC == 1) ? blockIdx.y : 0;
    const unsigned short* W = Wp + (size_t)n*M*256;

    __shared__ unsigned short As[2][128*32];
    __shared__ unsigned short Ws[2][M*32];

    int t = threadIdx.x, l = t & 63, w = t >> 6;
    int lr = l & 15, lk = l >> 4;
    int arow = t >> 1, aseg = t & 1;

    f32x4 acc[2][NJ];
    #pragma unroll
    for (int i = 0; i < 2; ++i)
        #pragma unroll
        for (int j = 0; j < NJ; ++j)
            acc[i][j] = (f32x4){0.f,0.f,0.f,0.f};

    bf16x8 au0, au1, wu0, wu1;
    auto loadA = [&](int k0, bf16x8 &u0, bf16x8 &u1) {
        const float* src;
        if (SRC == 0) {
            int gr = row0 + arow;
            src = (gr < B_TOT ? A0 + (size_t)gr*HH : A1 + (size_t)(gr - B_TOT)*HH) + k0 + aseg*16;
        } else {
            src = A0 + (((size_t)(row0 + arow))*NU + n)*HH + k0 + aseg*16;
        }
        const float4* s4 = (const float4*)src;
        float4 f0 = s4[0], f1 = s4[1], f2 = s4[2], f3 = s4[3];
        u0[0]=(short)f2bf(f0.x); u0[1]=(short)f2bf(f0.y); u0[2]=(short)f2bf(f0.z); u0[3]=(short)f2bf(f0.w);
        u0[4]=(short)f2bf(f1.x); u0[5]=(short)f2bf(f1.y); u0[6]=(short)f2bf(f1.z); u0[7]=(short)f2bf(f1.w);
        u1[0]=(short)f2bf(f2.x); u1[1]=(short)f2bf(f2.y); u1[2]=(short)f2bf(f2.z); u1[3]=(short)f2bf(f2.w);
        u1[4]=(short)f2bf(f3.x); u1[5]=(short)f2bf(f3.y); u1[6]=(short)f2bf(f3.z); u1[7]=(short)f2bf(f3.w);
        if (SRC == 1) {
            unsigned short* dp = hsb + ((size_t)n*B_TOT + row0 + arow)*256 + k0 + aseg*16;
            *(bf16x8*)dp       = u0;
            *(bf16x8*)(dp + 8) = u1;
        }
    };
    auto loadW = [&](int k0, bf16x8 &u0, bf16x8 &u1) {
        if (t < M*2) {
            const unsigned short* s = W + (size_t)(t >> 1)*256 + k0 + (t & 1)*16;
            u0 = ((const bf16x8*)s)[0];
            u1 = ((const bf16x8*)s)[1];
        }
    };

    loadA(0, au0, au1);
    loadW(0, wu0, wu1);

    for (int tt = 0; tt < 8; ++tt) {
        char* A_ = (char*)&As[tt & 1][0];
        char* W_ = (char*)&Ws[tt & 1][0];
        *(bf16x8*)(A_ + (aseg*2+0)*AREG + arow*16) = au0;
        *(bf16x8*)(A_ + (aseg*2+1)*AREG + arow*16) = au1;
        if (t < M*2) {
            int wrow = t >> 1, wseg = t & 1;
            *(bf16x8*)(W_ + (wseg*2+0)*WREG + wrow*16) = wu0;
            *(bf16x8*)(W_ + (wseg*2+1)*WREG + wrow*16) = wu1;
        }
        __syncthreads();
        if (tt + 1 < 8) {
            loadA((tt+1)*32, au0, au1);
            loadW((tt+1)*32, wu0, wu1);
        }
        bf16x8 a0 = *(bf16x8*)(A_ + lk*AREG + (w*32 + lr)*16);
        bf16x8 a1 = *(bf16x8*)(A_ + lk*AREG + (w*32 + 16 + lr)*16);
        bf16x8 bq[NJ];
        #pragma unroll
        for (int j = 0; j < NJ; ++j)
            bq[j] = *(bf16x8*)(W_ + lk*WREG + (j*16 + lr)*16);
        #pragma unroll
        for (int j = 0; j < NJ; ++j) {
            acc[0][j] = __builtin_amdgcn_mfma_f32_16x16x32_bf16(a0, bq[j], acc[0][j], 0, 0, 0);
            acc[1][j] = __builtin_amdgcn_mfma_f32_16x16x32_bf16(a1, bq[j], acc[1][j], 0, 0, 0);
        }
    }

    float* Cb = (SRC == 0) ? C : C + (size_t)n*B_TOT*16;
    #pragma unroll
    for (int i = 0; i < 2; ++i)
        #pragma unroll
        for (int j = 0; j < NJ; ++j)
            #pragma unroll
            for (int reg = 0; reg < 4; ++reg) {
                int r = row0 + w*32 + i*16 + lk*4 + reg;
                Cb[(size_t)r*M + j*16 + lr] = acc[i][j][reg];
            }
}

// ---------- scores -> softmax -> mask -> inputs ----------
__global__ __launch_bounds__(256) void score_mask_inputs(
    const float* __restrict__ KV,
    const float* __restrict__ qL,
    const float* __restrict__ bkey, const float* __restrict__ bval,
    unsigned short* __restrict__ inputs, float* __restrict__ maskf)
{
    int t  = threadIdx.x;
    int gb = blockIdx.x*32 + (t >> 3);
    int n  = t & 7, l = t & 63;

    float q[16];
    const float* qp = qL + ((size_t)n*B_TOT + gb)*16;
    #pragma unroll
    for (int i = 0; i < 4; ++i) *(float4*)&q[i*4] = ((const float4*)qp)[i];

    const float* kv0 = KV + (size_t)gb*48;
    const float* kv1 = KV + (size_t)(B_TOT + gb)*48;

    float s0 = 0.f, s1 = 0.f, sn = 0.f;
    #pragma unroll
    for (int k = 0; k < 16; ++k) {
        float bk = bkey[k];
        s0 += q[k]*(kv0[k] + bk);
        s1 += q[k]*(kv1[k] + bk);
        sn += q[k]*bk;
    }
    s0 *= 0.25f; s1 *= 0.25f; sn *= 0.25f;

    float mx = fmaxf(s0, fmaxf(s1, sn));
    float e0 = expf(s0-mx), e1 = expf(s1-mx), en = expf(sn-mx);
    float inv = 1.f/(e0+e1+en);
    float p0 = e0*inv, p1 = e1*inv, pn = en*inv;

    int rank = 0;
    #pragma unroll
    for (int m = 0; m < 8; ++m) {
        float sm = __shfl(sn, (l & ~7) + m, 64);
        if (sm > sn || (sm == sn && m < n)) rank++;
    }
    float mk = (rank < 4) ? 0.f : 1.f;
    maskf[(size_t)gb*8 + n] = mk;

    unsigned short* op = inputs + ((size_t)n*B_TOT + gb)*32;
    #pragma unroll
    for (int db = 0; db < 4; ++db) {
        bf16x8 o;
        #pragma unroll
        for (int e = 0; e < 8; ++e) {
            int d = db*8 + e;
            float bv = bval[d];
            float v = mk*(p0*(kv0[16+d]+bv) + p1*(kv1[16+d]+bv) + pn*bv);
            o[e] = (short)f2bf(v);
        }
        *(bf16x8*)&op[db*8] = o;
    }
}

// ---------- attention: q2k2 bf16 in, v2 fp8 in, ctx fp8 out ----------
__global__ __launch_bounds__(256) void attn_kernel(
    const unsigned short* __restrict__ QKb,   // [n][B][64] bf16
    const unsigned char*  __restrict__ V2,    // [n][B][1024] fp8
    unsigned char* __restrict__ CTX,          // [n][B][1024] fp8
    const float* __restrict__ maskf, int Bc, int c0)
{
    int wid = threadIdx.x >> 6;
    int l   = threadIdx.x & 63;
    int b   = blockIdx.x*4 + wid;
    int gb  = c0 + b;

    __shared__ float qk[4][8][64];
    __shared__ float P[4][4][8][8];

    for (int it = 0; it < 8; ++it) {
        int idx = l + 64*it;
        int n = idx >> 6, c = idx & 63;
        qk[wid][n][c] = bf2f(QKb[((size_t)n*Bc + b)*64 + c]);
    }
    __syncthreads();

    for (int it = 0; it < 4; ++it) {
        int idx = l + 64*it;
        int h = idx >> 6, n = (idx >> 3) & 7, m = idx & 7;
        float s = 0.f;
        #pragma unroll
        for (int dk = 0; dk < 8; ++dk) s += qk[wid][n][h*8 + dk]*qk[wid][m][32 + h*8 + dk];
        P[wid][h][n][m] = s * 0.35355339059327373f;
    }
    __syncthreads();

    if (l < 32) {
        int h = l >> 3, n = l & 7;
        float mx = -1e30f;
        for (int m = 0; m < 8; ++m) mx = fmaxf(mx, P[wid][h][n][m]);
        float e[8], sum = 0.f;
        for (int m = 0; m < 8; ++m) { e[m] = expf(P[wid][h][n][m]-mx); sum += e[m]; }
        float scl = maskf[(size_t)gb*8 + n] / sum;
        for (int m = 0; m < 8; ++m) P[wid][h][n][m] = e[m]*scl;
    }
    __syncthreads();

    #pragma unroll
    for (int it = 0; it < 2; ++it) {
        int colb = (l + 64*it)*8;
        int h = colb >> 8;
        float acc[8][8];
        #pragma unroll
        for (int n = 0; n < 8; ++n)
            #pragma unroll
            for (int c = 0; c < 8; ++c) acc[n][c] = 0.f;
        for (int m = 0; m < 8; ++m) {
            uint2 v8 = *(const uint2*)&V2[((size_t)m*Bc + b)*1024 + colb];
            float vf[8];
            vf[0] = __builtin_amdgcn_cvt_f32_fp8(v8.x, 0);
            vf[1] = __builtin_amdgcn_cvt_f32_fp8(v8.x, 1);
            vf[2] = __builtin_amdgcn_cvt_f32_fp8(v8.x, 2);
            vf[3] = __builtin_amdgcn_cvt_f32_fp8(v8.x, 3);
            vf[4] = __builtin_amdgcn_cvt_f32_fp8(v8.y, 0);
            vf[5] = __builtin_amdgcn_cvt_f32_fp8(v8.y, 1);
            vf[6] = __builtin_amdgcn_cvt_f32_fp8(v8.y, 2);
            vf[7] = __builtin_amdgcn_cvt_f32_fp8(v8.y, 3);
            #pragma unroll
            for (int n = 0; n < 8; ++n) {
                float p = P[wid][h][n][m];
                #pragma unroll
                for (int c = 0; c < 8; ++c) acc[n][c] += p*vf[c];
            }
        }
        #pragma unroll
        for (int n = 0; n < 8; ++n) {
            int lo = __builtin_amdgcn_cvt_pk_fp8_f32(acc[n][0], acc[n][1], 0,  false);
            lo     = __builtin_amdgcn_cvt_pk_fp8_f32(acc[n][2], acc[n][3], lo, true);
            int hi = __builtin_amdgcn_cvt_pk_fp8_f32(acc[n][4], acc[n][5], 0,  false);
            hi     = __builtin_amdgcn_cvt_pk_fp8_f32(acc[n][6], acc[n][7], hi, true);
            uint2 o; o.x = (unsigned int)lo; o.y = (unsigned int)hi;
            *(uint2*)&CTX[((size_t)n*Bc + b)*1024 + colb] = o;
        }
    }
}

// ---------- bf16 MFMA GEMM (MODE 0: gates+GRU; MODE 1: qkv->QKb/V2fp8) ----------
template<int MODE, int TN>
__global__ __launch_bounds__(512) void gemm_mfma(
    const unsigned short* __restrict__ hsb,
    const unsigned short* __restrict__ inputs,
    const unsigned short* __restrict__ Asrc,
    const unsigned short* __restrict__ Wp,
    unsigned short* __restrict__ hsnb,
    unsigned short* __restrict__ QKb,
    unsigned char*  __restrict__ V2,
    int Bc, int c0)
{
    constexpr int KW   = (MODE==0) ? 288 : 256;
    constexpr int M    = (MODE==0) ? 1024 : 1152;
    constexpr int BM   = 256;
    constexpr int NJ   = TN/16;
    constexpr int NT   = KW/32;
    constexpr int CB   = M/TN;
    constexpr int AREG = BM*16;
    constexpr int WREG = TN*16;

    int bid = blockIdx.x;
    int n   = bid & 7;
    int loc = bid >> 3;
    int col0 = (loc % CB) * TN;
    int row0 = (loc / CB) * BM;

    __shared__ unsigned short As[2][BM*32];
    __shared__ unsigned short Ws[2][TN*32];

    int t = threadIdx.x;
    int l = t & 63, w = t >> 6;
    int lr = l & 15, lk = l >> 4;

    int arow = t >> 1, aseg = t & 1;
    int wrow = t & 127, wslot = t >> 7;

    f32x4 acc[2][NJ];
    #pragma unroll
    for (int i = 0; i < 2; ++i)
        #pragma unroll
        for (int j = 0; j < NJ; ++j)
            acc[i][j] = (f32x4){0.f,0.f,0.f,0.f};

    bf16x8 aA0, aA1, wA0;
    bf16x8 aB0, aB1, wB0;

    auto loadA = [&](int k0, bf16x8 &u0, bf16x8 &u1) {
        const unsigned short* s;
        if (MODE == 0) {
            if (k0 < 256) s = hsb + ((size_t)n*B_TOT + c0 + row0 + arow)*256 + k0 + aseg*16;
            else          s = inputs + ((size_t)n*B_TOT + c0 + row0 + arow)*32 + aseg*16;
        } else {
            s = Asrc + ((size_t)n*Bc + row0 + arow)*256 + k0 + aseg*16;
        }
        u0 = ((const bf16x8*)s)[0];
        u1 = ((const bf16x8*)s)[1];
    };
    auto loadW = [&](int k0, bf16x8 &u0) {
        const unsigned short* s = Wp + ((size_t)n*M + col0 + wrow)*(size_t)KW + k0 + wslot*8;
        u0 = *(const bf16x8*)s;
    };
    auto stage = [&](char* A_, char* W_, bf16x8 a0, bf16x8 a1, bf16x8 w0) {
        *(bf16x8*)(A_ + (aseg*2+0)*AREG + arow*16) = a0;
        *(bf16x8*)(A_ + (aseg*2+1)*AREG + arow*16) = a1;
        *(bf16x8*)(W_ + wslot*WREG + wrow*16) = w0;
    };
    auto compute = [&](char* A_, char* W_) {
        bf16x8 a0 = *(bf16x8*)(A_ + lk*AREG + (w*32 + lr)*16);
        bf16x8 a1 = *(bf16x8*)(A_ + lk*AREG + (w*32 + 16 + lr)*16);
        #pragma unroll
        for (int j = 0; j < NJ; ++j) {
            bf16x8 b = *(bf16x8*)(W_ + lk*WREG + (j*16 + lr)*16);
            acc[0][j] = __builtin_amdgcn_mfma_f32_16x16x32_bf16(a0, b, acc[0][j], 0, 0, 0);
            acc[1][j] = __builtin_amdgcn_mfma_f32_16x16x32_bf16(a1, b, acc[1][j], 0, 0, 0);
        }
    };

    char* AE = (char*)&As[0][0]; char* AO = (char*)&As[1][0];
    char* WE = (char*)&Ws[0][0]; char* WO = (char*)&Ws[1][0];

    loadA(0,  aA0, aA1);  loadW(0,  wA0);
    loadA(32, aB0, aB1);  loadW(32, wB0);

    int tt = 0;
    for (; tt + 1 < NT; tt += 2) {
        stage(AE, WE, aA0, aA1, wA0);
        __syncthreads();
        if (tt + 2 < NT) { loadA((tt+2)*32, aA0, aA1); loadW((tt+2)*32, wA0); }
        compute(AE, WE);

        stage(AO, WO, aB0, aB1, wB0);
        __syncthreads();
        if (tt + 3 < NT) { loadA((tt+3)*32, aB0, aB1); loadW((tt+3)*32, wB0); }
        compute(AO, WO);
    }
    if (tt < NT) {
        stage(AE, WE, aA0, aA1, wA0);
        __syncthreads();
        compute(AE, WE);
    }

    if constexpr (MODE == 0) {
        #pragma unroll
        for (int i = 0; i < 2; ++i) {
            int rbase = row0 + w*32 + i*16 + lk*4;
            #pragma unroll
            for (int half = 0; half < 2; ++half) {
                int o = (col0 >> 2) + half*16 + lr;
                #pragma unroll
                for (int reg = 0; reg < 4; ++reg) {
                    int r = rbase + reg;
                    float rs = acc[i][0+half][reg];
                    float zs = acc[i][2+half][reg];
                    float gx = acc[i][4+half][reg];
                    float gh = acc[i][6+half][reg];
                    float hold = bf2f(hsb[((size_t)n*B_TOT + c0 + r)*256 + o]);
                    float rr = sigm(rs), z = sigm(zs);
                    float nn = tanhf(gx + rr*gh);
                    float h  = nn + z*(hold - nn);
                    hsnb[((size_t)n*Bc + r)*256 + o] = f2bf(h);
                }
            }
        }
    } else {
        #pragma unroll
        for (int i = 0; i < 2; ++i) {
            #pragma unroll
            for (int j = 0; j < NJ; ++j) {
                int c = col0 + j*16 + lr;
                #pragma unroll
                for (int reg = 0; reg < 4; ++reg) {
                    int r = row0 + w*32 + i*16 + lk*4 + reg;
                    float v = acc[i][j][reg];
                    if (c < 64) QKb[((size_t)n*Bc + r)*64 + c] = f2bf(v);
                    else        V2 [((size_t)n*Bc + r)*1024 + (c-64)] = f2fp8(v);
                }
            }
        }
    }
}

// ---------- MODE 2: fp8 x fp8 GEMM, BM=256 x TN=256 (CB=1), 16 waves ----------
__global__ __launch_bounds__(1024) void gemm_out_fp8(
    const unsigned char* __restrict__ CTX,   // [n][B][1024] fp8
    const unsigned char* __restrict__ Wo8,   // [n][256][1024] fp8
    const unsigned short* __restrict__ hsnb,
    const float* __restrict__ hs_glob,
    const float* __restrict__ maskf,
    float* __restrict__ outp,
    int Bc, int c0)
{
    constexpr int BM = 256, NT = 32;
    constexpr int AREG = BM*8;    // bytes per A k-slot region (8 fp8/row)
    constexpr int WREG = 256*8;

    int bid = blockIdx.x;
    int n   = bid & 7;
    int row0 = (bid >> 3) * BM;

    __shared__ unsigned char As[2][BM*32];   // 8KB each
    __shared__ unsigned char Ws[2][256*32];  // 8KB each

    int t = threadIdx.x;
    int l = t & 63, w = t >> 6;              // 16 waves
    int wr = w >> 2, wc = w & 3;             // wave sub-tile: rows wr*64, cols wc*64
    int lr = l & 15, lk = l >> 4;
    int arow = t >> 2, aslot = t & 3;        // 256 rows x 4 slots, 8B/thread

    f32x4 acc[4][4];
    #pragma unroll
    for (int i = 0; i < 4; ++i)
        #pragma unroll
        for (int j = 0; j < 4; ++j)
            acc[i][j] = (f32x4){0.f,0.f,0.f,0.f};

    u64 aA0, wA0, aB0, wB0;

    auto loadA = [&](int k0, u64 &u0) {
        u0 = *(const u64*)(CTX + ((size_t)n*Bc + row0 + arow)*1024 + k0 + aslot*8);
    };
    auto loadW = [&](int k0, u64 &u0) {
        u0 = *(const u64*)(Wo8 + ((size_t)n*256 + arow)*1024 + k0 + aslot*8);
    };
    auto stage = [&](unsigned char* A_, unsigned char* W_, u64 a0, u64 w0) {
        *(u64*)(A_ + aslot*AREG + arow*8) = a0;
        *(u64*)(W_ + aslot*WREG + arow*8) = w0;
    };
    auto compute = [&](unsigned char* A_, unsigned char* W_) {
        long a[4];
        #pragma unroll
        for (int i = 0; i < 4; ++i)
            a[i] = *(const long*)(A_ + lk*AREG + (wr*64 + i*16 + lr)*8);
        #pragma unroll
        for (int j = 0; j < 4; ++j) {
            long b = *(const long*)(W_ + lk*WREG + (wc*64 + j*16 + lr)*8);
            #pragma unroll
            for (int i = 0; i < 4; ++i)
                acc[i][j] = __builtin_amdgcn_mfma_f32_16x16x32_fp8_fp8(a[i], b, acc[i][j], 0, 0, 0);
        }
    };

    unsigned char* AE = &As[0][0]; unsigned char* AO = &As[1][0];
    unsigned char* WE = &Ws[0][0]; unsigned char* WO = &Ws[1][0];

    loadA(0,  aA0);  loadW(0,  wA0);
    loadA(32, aB0);  loadW(32, wB0);

    for (int tt = 0; tt < NT; tt += 2) {       // NT=32 even
        stage(AE, WE, aA0, wA0);
        __syncthreads();
        if (tt + 2 < NT) { loadA((tt+2)*32, aA0); loadW((tt+2)*32, wA0); }
        compute(AE, WE);

        stage(AO, WO, aB0, wB0);
        __syncthreads();
        if (tt + 3 < NT) { loadA((tt+3)*32, aB0); loadW((tt+3)*32, wB0); }
        compute(AO, WO);
    }

    #pragma unroll
    for (int i = 0; i < 4; ++i) {
        #pragma unroll
        for (int reg = 0; reg < 4; ++reg) {
            int r = row0 + wr*64 + i*16 + lk*4 + reg;
            float mkv = maskf[(size_t)(c0 + r)*8 + n];
            size_t gi0 = (((size_t)(c0 + r))*NU + n)*HH;
            #pragma unroll
            for (int j = 0; j < 4; ++j) {
                int c = wc*64 + j*16 + lr;
                float v;
                if (mkv != 0.f) v = acc[i][j][reg] + bf2f(hsnb[((size_t)n*Bc + r)*256 + c]);
                else            v = hs_glob[gi0 + c];
                outp[gi0 + c] = v;
            }
        }
    }
}

extern "C" void kernel_launch(void* const* d_in, const int* in_sizes, int n_in,
                              void* d_out, int out_size, void* d_ws, size_t ws_size,
                              hipStream_t stream)
{
    const float* x1   = (const float*)d_in[0];
    const float* x2   = (const float*)d_in[1];
    const float* hs   = (const float*)d_in[2];
    const float* Wkey = (const float*)d_in[3];
    const float* bkey = (const float*)d_in[4];
    const float* Wval = (const float*)d_in[5];
    const float* bval = (const float*)d_in[6];
    const float* Wq   = (const float*)d_in[7];
    const float* Wq_  = (const float*)d_in[8];
    const float* Wk_  = (const float*)d_in[9];
    const float* Wv_  = (const float*)d_in[10];
    const float* Wout = (const float*)d_in[11];
    const float* Wx2h = (const float*)d_in[12];
    const float* Wh2h = (const float*)d_in[13];
    float* out = (float*)d_out;

    char* ws = (char*)d_ws;
    size_t off = 0;
    auto alloc = [&](size_t bytes) -> void* {
        void* p = (void*)(ws + off);
        off = (off + bytes + 255) & ~(size_t)255;
        return p;
    };
    unsigned short* Wg     = (unsigned short*)alloc((size_t)8*1024*288*2);
    unsigned short* Wqkv   = (unsigned short*)alloc((size_t)8*1152*256*2);
    unsigned char*  Wo8    = (unsigned char*) alloc((size_t)8*256*1024);
    unsigned short* Wkv    = (unsigned short*)alloc((size_t)48*256*2);
    unsigned short* Wqt    = (unsigned short*)alloc((size_t)8*16*256*2);
    unsigned short* inputs = (unsigned short*)alloc((size_t)8*B_TOT*32*2);
    float*          maskf  = (float*)         alloc((size_t)B_TOT*8*4);
    float*          KV     = (float*)         alloc((size_t)2*B_TOT*48*4);
    float*          qL     = (float*)         alloc((size_t)8*B_TOT*16*4);
    unsigned short* hsb    = (unsigned short*)alloc((size_t)8*B_TOT*256*2);
    size_t persist = off;

    const size_t perB = 8*256*2 + 8*64*2 + 8*1024 + 8*1024;
    int Bc = B_TOT;
    while (Bc > 256 && persist + (size_t)Bc*perB + 65536 > ws_size) Bc >>= 1;
    unsigned short* hsnb = (unsigned short*)alloc((size_t)8*Bc*256*2);
    unsigned short* QKb  = (unsigned short*)alloc((size_t)8*Bc*64*2);
    unsigned char*  V2   = (unsigned char*) alloc((size_t)8*Bc*1024);
    unsigned char*  CTX  = (unsigned char*) alloc((size_t)8*Bc*1024);

    const long long packN = (long long)TG + TQ + TO + TK + TL;
    pack_all<<<(int)((packN + 255)/256), 256, 0, stream>>>(
        Wh2h, Wx2h, Wq_, Wk_, Wv_, Wout, Wkey, Wval, Wq,
        Wg, Wqkv, Wo8, Wkv, Wqt);

    small_gemm<0><<<dim3(2*B_TOT/128), 256, 0, stream>>>(x1, x2, Wkv, KV, nullptr);
    small_gemm<1><<<dim3(B_TOT/128, 8), 256, 0, stream>>>(hs, nullptr, Wqt, qL, hsb);
    score_mask_inputs<<<B_TOT/32, 256, 0, stream>>>(KV, qL, bkey, bval, inputs, maskf);

    for (int c0 = 0; c0 < B_TOT; c0 += Bc) {
        int RB = Bc / 256;
        gemm_mfma<0,128><<<dim3(RB*8*8), 512, 0, stream>>>(
            hsb, inputs, nullptr, Wg, hsnb, nullptr, nullptr, Bc, c0);
        gemm_mfma<1,128><<<dim3(RB*9*8), 512, 0, stream>>>(
            hsb, nullptr, hsnb, Wqkv, nullptr, QKb, V2, Bc, c0);
        attn_kernel<<<Bc/4, 256, 0, stream>>>(QKb, V2, CTX, maskf, Bc, c0);
        gemm_out_fp8<<<dim3(RB*8), 1024, 0, stream>>>(
            CTX, Wo8, hsnb, hs, maskf, out, Bc, c0);
    }
}

// Round 18
// 297.420 us; speedup vs baseline: 1.0360x; 1.0360x over previous
//
#include <hip/hip_runtime.h>
#include <math.h>

// BRIMCell forward — bf16 MFMA front GEMMs; fp8(e4m3) v2/ctx stream.
// R18 = R16 base + mask exploitation: attn skips CTX writes for masked n;
// M2 masked rows read hsb (bf16) not hs (fp32). M2 = TN=128 CB=2 (R16 proven).

#define B_TOT 8192
#define NU 8
#define HH 256

typedef __attribute__((ext_vector_type(8))) short bf16x8;
typedef __attribute__((ext_vector_type(4))) float f32x4;
typedef unsigned long long u64;

__device__ __forceinline__ float sigm(float x){ return 1.0f/(1.0f+expf(-x)); }

__device__ __forceinline__ unsigned short f2bf(float f){
    union { float f; unsigned int u; } v; v.f = f;
    unsigned int r = v.u + 0x7fffu + ((v.u >> 16) & 1u);
    return (unsigned short)(r >> 16);
}
__device__ __forceinline__ float bf2f(unsigned short h){
    union { unsigned int u; float f; } v; v.u = ((unsigned int)h) << 16;
    return v.f;
}
__device__ __forceinline__ unsigned char f2fp8(float v){
    int p = __builtin_amdgcn_cvt_pk_fp8_f32(v, v, 0, false);
    return (unsigned char)(p & 0xff);
}

// ---------- fused weight packing ----------
#define TG (8*1024*288)
#define TQ (8*1152*256)
#define TO (8*256*1024)
#define TK (48*256)
#define TL (8*16*256)
__global__ void pack_all(const float* __restrict__ Wh2h, const float* __restrict__ Wx2h,
                         const float* __restrict__ Wq_,  const float* __restrict__ Wk_,
                         const float* __restrict__ Wv_,  const float* __restrict__ Wout,
                         const float* __restrict__ Wkey, const float* __restrict__ Wval,
                         const float* __restrict__ Wq,
                         unsigned short* __restrict__ Wg, unsigned short* __restrict__ Wqkv,
                         unsigned char* __restrict__ Wo8, unsigned short* __restrict__ Wkv,
                         unsigned short* __restrict__ Wqt)
{
    long long gidx = (long long)blockIdx.x*256 + threadIdx.x;
    if (gidx < TG) {
        int idx = (int)gidx;
        int k  = idx % 288;
        int pc = (idx / 288) % 1024;
        int n  = idx / (288*1024);
        int cb = pc >> 7, r = pc & 127;
        int g = r >> 5, ol = r & 31;
        int o = cb*32 + ol;
        float v = 0.f;
        if (g == 0)      v = (k < 256) ? Wh2h[((size_t)n*256 + k)*768 + o]
                                       : Wx2h[((size_t)n*32 + (k-256))*768 + o];
        else if (g == 1) v = (k < 256) ? Wh2h[((size_t)n*256 + k)*768 + 256 + o]
                                       : Wx2h[((size_t)n*32 + (k-256))*768 + 256 + o];
        else if (g == 2) v = (k >= 256) ? Wx2h[((size_t)n*32 + (k-256))*768 + 512 + o] : 0.f;
        else             v = (k < 256) ? Wh2h[((size_t)n*256 + k)*768 + 512 + o] : 0.f;
        Wg[idx] = f2bf(v);
        return;
    }
    gidx -= TG;
    if (gidx < TQ) {
        int idx = (int)gidx;
        int k = idx % 256;
        int c = (idx / 256) % 1152;
        int n = idx / (256*1152);
        float v = 0.f;
        if (c < 32)        v = Wq_[((size_t)n*256+k)*32 + c];
        else if (c < 64)   v = Wk_[((size_t)n*256+k)*32 + (c-32)];
        else if (c < 1088) v = Wv_[((size_t)n*256+k)*1024 + (c-64)];
        Wqkv[idx] = f2bf(v);
        return;
    }
    gidx -= TQ;
    if (gidx < TO) {                 // Wout -> fp8, [n][c(256)][k(1024)]
        int idx = (int)gidx;
        int k = idx % 1024;
        int c = (idx / 1024) % 256;
        int n = idx / (1024*256);
        Wo8[idx] = f2fp8(Wout[((size_t)n*1024 + k)*256 + c]);
        return;
    }
    gidx -= TO;
    if (gidx < TK) {
        int idx = (int)gidx;
        int k = idx & 255, c = idx >> 8;
        float v = (c < 16) ? Wkey[k*16 + c] : Wval[k*32 + (c-16)];
        Wkv[(size_t)c*256 + k] = f2bf(v);
        return;
    }
    gidx -= TK;
    if (gidx < TL) {
        int idx = (int)gidx;
        int k = idx & 255, c = (idx >> 8) & 15, n = idx >> 12;
        Wqt[((size_t)n*16 + c)*256 + k] = f2bf(Wq[((size_t)n*256 + k)*16 + c]);
    }
}

// ---------- small MFMA GEMM for stage-A precursors ----------
template<int SRC>
__global__ __launch_bounds__(256) void small_gemm(
    const float* __restrict__ A0, const float* __restrict__ A1,
    const unsigned short* __restrict__ Wp, float* __restrict__ C,
    unsigned short* __restrict__ hsb)
{
    constexpr int M    = (SRC == 0) ? 48 : 16;
    constexpr int NJ   = M/16;
    constexpr int AREG = 128*16;
    constexpr int WREG = M*16;
    int row0 = blockIdx.x * 128;
    int n = (SRC == 1) ? blockIdx.y : 0;
    const unsigned short* W = Wp + (size_t)n*M*256;

    __shared__ unsigned short As[2][128*32];
    __shared__ unsigned short Ws[2][M*32];

    int t = threadIdx.x, l = t & 63, w = t >> 6;
    int lr = l & 15, lk = l >> 4;
    int arow = t >> 1, aseg = t & 1;

    f32x4 acc[2][NJ];
    #pragma unroll
    for (int i = 0; i < 2; ++i)
        #pragma unroll
        for (int j = 0; j < NJ; ++j)
            acc[i][j] = (f32x4){0.f,0.f,0.f,0.f};

    bf16x8 au0, au1, wu0, wu1;
    auto loadA = [&](int k0, bf16x8 &u0, bf16x8 &u1) {
        const float* src;
        if (SRC == 0) {
            int gr = row0 + arow;
            src = (gr < B_TOT ? A0 + (size_t)gr*HH : A1 + (size_t)(gr - B_TOT)*HH) + k0 + aseg*16;
        } else {
            src = A0 + (((size_t)(row0 + arow))*NU + n)*HH + k0 + aseg*16;
        }
        const float4* s4 = (const float4*)src;
        float4 f0 = s4[0], f1 = s4[1], f2 = s4[2], f3 = s4[3];
        u0[0]=(short)f2bf(f0.x); u0[1]=(short)f2bf(f0.y); u0[2]=(short)f2bf(f0.z); u0[3]=(short)f2bf(f0.w);
        u0[4]=(short)f2bf(f1.x); u0[5]=(short)f2bf(f1.y); u0[6]=(short)f2bf(f1.z); u0[7]=(short)f2bf(f1.w);
        u1[0]=(short)f2bf(f2.x); u1[1]=(short)f2bf(f2.y); u1[2]=(short)f2bf(f2.z); u1[3]=(short)f2bf(f2.w);
        u1[4]=(short)f2bf(f3.x); u1[5]=(short)f2bf(f3.y); u1[6]=(short)f2bf(f3.z); u1[7]=(short)f2bf(f3.w);
        if (SRC == 1) {
            unsigned short* dp = hsb + ((size_t)n*B_TOT + row0 + arow)*256 + k0 + aseg*16;
            *(bf16x8*)dp       = u0;
            *(bf16x8*)(dp + 8) = u1;
        }
    };
    auto loadW = [&](int k0, bf16x8 &u0, bf16x8 &u1) {
        if (t < M*2) {
            const unsigned short* s = W + (size_t)(t >> 1)*256 + k0 + (t & 1)*16;
            u0 = ((const bf16x8*)s)[0];
            u1 = ((const bf16x8*)s)[1];
        }
    };

    loadA(0, au0, au1);
    loadW(0, wu0, wu1);

    for (int tt = 0; tt < 8; ++tt) {
        char* A_ = (char*)&As[tt & 1][0];
        char* W_ = (char*)&Ws[tt & 1][0];
        *(bf16x8*)(A_ + (aseg*2+0)*AREG + arow*16) = au0;
        *(bf16x8*)(A_ + (aseg*2+1)*AREG + arow*16) = au1;
        if (t < M*2) {
            int wrow = t >> 1, wseg = t & 1;
            *(bf16x8*)(W_ + (wseg*2+0)*WREG + wrow*16) = wu0;
            *(bf16x8*)(W_ + (wseg*2+1)*WREG + wrow*16) = wu1;
        }
        __syncthreads();
        if (tt + 1 < 8) {
            loadA((tt+1)*32, au0, au1);
            loadW((tt+1)*32, wu0, wu1);
        }
        bf16x8 a0 = *(bf16x8*)(A_ + lk*AREG + (w*32 + lr)*16);
        bf16x8 a1 = *(bf16x8*)(A_ + lk*AREG + (w*32 + 16 + lr)*16);
        bf16x8 bq[NJ];
        #pragma unroll
        for (int j = 0; j < NJ; ++j)
            bq[j] = *(bf16x8*)(W_ + lk*WREG + (j*16 + lr)*16);
        #pragma unroll
        for (int j = 0; j < NJ; ++j) {
            acc[0][j] = __builtin_amdgcn_mfma_f32_16x16x32_bf16(a0, bq[j], acc[0][j], 0, 0, 0);
            acc[1][j] = __builtin_amdgcn_mfma_f32_16x16x32_bf16(a1, bq[j], acc[1][j], 0, 0, 0);
        }
    }

    float* Cb = (SRC == 0) ? C : C + (size_t)n*B_TOT*16;
    #pragma unroll
    for (int i = 0; i < 2; ++i)
        #pragma unroll
        for (int j = 0; j < NJ; ++j)
            #pragma unroll
            for (int reg = 0; reg < 4; ++reg) {
                int r = row0 + w*32 + i*16 + lk*4 + reg;
                Cb[(size_t)r*M + j*16 + lr] = acc[i][j][reg];
            }
}

// ---------- scores -> softmax -> mask -> inputs ----------
__global__ __launch_bounds__(256) void score_mask_inputs(
    const float* __restrict__ KV,
    const float* __restrict__ qL,
    const float* __restrict__ bkey, const float* __restrict__ bval,
    unsigned short* __restrict__ inputs, float* __restrict__ maskf)
{
    int t  = threadIdx.x;
    int gb = blockIdx.x*32 + (t >> 3);
    int n  = t & 7, l = t & 63;

    float q[16];
    const float* qp = qL + ((size_t)n*B_TOT + gb)*16;
    #pragma unroll
    for (int i = 0; i < 4; ++i) *(float4*)&q[i*4] = ((const float4*)qp)[i];

    const float* kv0 = KV + (size_t)gb*48;
    const float* kv1 = KV + (size_t)(B_TOT + gb)*48;

    float s0 = 0.f, s1 = 0.f, sn = 0.f;
    #pragma unroll
    for (int k = 0; k < 16; ++k) {
        float bk = bkey[k];
        s0 += q[k]*(kv0[k] + bk);
        s1 += q[k]*(kv1[k] + bk);
        sn += q[k]*bk;
    }
    s0 *= 0.25f; s1 *= 0.25f; sn *= 0.25f;

    float mx = fmaxf(s0, fmaxf(s1, sn));
    float e0 = expf(s0-mx), e1 = expf(s1-mx), en = expf(sn-mx);
    float inv = 1.f/(e0+e1+en);
    float p0 = e0*inv, p1 = e1*inv, pn = en*inv;

    int rank = 0;
    #pragma unroll
    for (int m = 0; m < 8; ++m) {
        float sm = __shfl(sn, (l & ~7) + m, 64);
        if (sm > sn || (sm == sn && m < n)) rank++;
    }
    float mk = (rank < 4) ? 0.f : 1.f;
    maskf[(size_t)gb*8 + n] = mk;

    unsigned short* op = inputs + ((size_t)n*B_TOT + gb)*32;
    #pragma unroll
    for (int db = 0; db < 4; ++db) {
        bf16x8 o;
        #pragma unroll
        for (int e = 0; e < 8; ++e) {
            int d = db*8 + e;
            float bv = bval[d];
            float v = mk*(p0*(kv0[16+d]+bv) + p1*(kv1[16+d]+bv) + pn*bv);
            o[e] = (short)f2bf(v);
        }
        *(bf16x8*)&op[db*8] = o;
    }
}

// ---------- attention: q2k2 bf16 in, v2 fp8 in, ctx fp8 out (active n only) ----------
__global__ __launch_bounds__(256) void attn_kernel(
    const unsigned short* __restrict__ QKb,   // [n][B][64] bf16
    const unsigned char*  __restrict__ V2,    // [n][B][1024] fp8
    unsigned char* __restrict__ CTX,          // [n][B][1024] fp8
    const float* __restrict__ maskf, int Bc, int c0)
{
    int wid = threadIdx.x >> 6;
    int l   = threadIdx.x & 63;
    int b   = blockIdx.x*4 + wid;
    int gb  = c0 + b;

    __shared__ float qk[4][8][64];
    __shared__ float P[4][4][8][8];
    __shared__ float mk[4][8];

    for (int it = 0; it < 8; ++it) {
        int idx = l + 64*it;
        int n = idx >> 6, c = idx & 63;
        qk[wid][n][c] = bf2f(QKb[((size_t)n*Bc + b)*64 + c]);
    }
    if (l < 8) mk[wid][l] = maskf[(size_t)gb*8 + l];
    __syncthreads();

    for (int it = 0; it < 4; ++it) {
        int idx = l + 64*it;
        int h = idx >> 6, n = (idx >> 3) & 7, m = idx & 7;
        float s = 0.f;
        #pragma unroll
        for (int dk = 0; dk < 8; ++dk) s += qk[wid][n][h*8 + dk]*qk[wid][m][32 + h*8 + dk];
        P[wid][h][n][m] = s * 0.35355339059327373f;
    }
    __syncthreads();

    if (l < 32) {
        int h = l >> 3, n = l & 7;
        float mx = -1e30f;
        for (int m = 0; m < 8; ++m) mx = fmaxf(mx, P[wid][h][n][m]);
        float e[8], sum = 0.f;
        for (int m = 0; m < 8; ++m) { e[m] = expf(P[wid][h][n][m]-mx); sum += e[m]; }
        float scl = mk[wid][n] / sum;
        for (int m = 0; m < 8; ++m) P[wid][h][n][m] = e[m]*scl;
    }
    __syncthreads();

    #pragma unroll
    for (int it = 0; it < 2; ++it) {
        int colb = (l + 64*it)*8;
        int h = colb >> 8;
        float acc[8][8];
        #pragma unroll
        for (int n = 0; n < 8; ++n)
            #pragma unroll
            for (int c = 0; c < 8; ++c) acc[n][c] = 0.f;
        for (int m = 0; m < 8; ++m) {
            uint2 v8 = *(const uint2*)&V2[((size_t)m*Bc + b)*1024 + colb];
            float vf[8];
            vf[0] = __builtin_amdgcn_cvt_f32_fp8(v8.x, 0);
            vf[1] = __builtin_amdgcn_cvt_f32_fp8(v8.x, 1);
            vf[2] = __builtin_amdgcn_cvt_f32_fp8(v8.x, 2);
            vf[3] = __builtin_amdgcn_cvt_f32_fp8(v8.x, 3);
            vf[4] = __builtin_amdgcn_cvt_f32_fp8(v8.y, 0);
            vf[5] = __builtin_amdgcn_cvt_f32_fp8(v8.y, 1);
            vf[6] = __builtin_amdgcn_cvt_f32_fp8(v8.y, 2);
            vf[7] = __builtin_amdgcn_cvt_f32_fp8(v8.y, 3);
            #pragma unroll
            for (int n = 0; n < 8; ++n) {
                float p = P[wid][h][n][m];
                #pragma unroll
                for (int c = 0; c < 8; ++c) acc[n][c] += p*vf[c];
            }
        }
        // write ONLY active units' ctx (masked rows are discarded in the out
        // GEMM epilogue; stale fp8 bytes there are finite and never used)
        #pragma unroll
        for (int n = 0; n < 8; ++n) {
            if (mk[wid][n] != 0.f) {
                int lo = __builtin_amdgcn_cvt_pk_fp8_f32(acc[n][0], acc[n][1], 0,  false);
                lo     = __builtin_amdgcn_cvt_pk_fp8_f32(acc[n][2], acc[n][3], lo, true);
                int hi = __builtin_amdgcn_cvt_pk_fp8_f32(acc[n][4], acc[n][5], 0,  false);
                hi     = __builtin_amdgcn_cvt_pk_fp8_f32(acc[n][6], acc[n][7], hi, true);
                uint2 o; o.x = (unsigned int)lo; o.y = (unsigned int)hi;
                *(uint2*)&CTX[((size_t)n*Bc + b)*1024 + colb] = o;
            }
        }
    }
}

// ---------- bf16 MFMA GEMM (MODE 0: gates+GRU; MODE 1: qkv->QKb/V2fp8) ----------
template<int MODE, int TN>
__global__ __launch_bounds__(512) void gemm_mfma(
    const unsigned short* __restrict__ hsb,
    const unsigned short* __restrict__ inputs,
    const unsigned short* __restrict__ Asrc,
    const unsigned short* __restrict__ Wp,
    unsigned short* __restrict__ hsnb,
    unsigned short* __restrict__ QKb,
    unsigned char*  __restrict__ V2,
    int Bc, int c0)
{
    constexpr int KW   = (MODE==0) ? 288 : 256;
    constexpr int M    = (MODE==0) ? 1024 : 1152;
    constexpr int BM   = 256;
    constexpr int NJ   = TN/16;
    constexpr int NT   = KW/32;
    constexpr int CB   = M/TN;
    constexpr int AREG = BM*16;
    constexpr int WREG = TN*16;

    int bid = blockIdx.x;
    int n   = bid & 7;
    int loc = bid >> 3;
    int col0 = (loc % CB) * TN;
    int row0 = (loc / CB) * BM;

    __shared__ unsigned short As[2][BM*32];
    __shared__ unsigned short Ws[2][TN*32];

    int t = threadIdx.x;
    int l = t & 63, w = t >> 6;
    int lr = l & 15, lk = l >> 4;

    int arow = t >> 1, aseg = t & 1;
    int wrow = t & 127, wslot = t >> 7;

    f32x4 acc[2][NJ];
    #pragma unroll
    for (int i = 0; i < 2; ++i)
        #pragma unroll
        for (int j = 0; j < NJ; ++j)
            acc[i][j] = (f32x4){0.f,0.f,0.f,0.f};

    bf16x8 aA0, aA1, wA0;
    bf16x8 aB0, aB1, wB0;

    auto loadA = [&](int k0, bf16x8 &u0, bf16x8 &u1) {
        const unsigned short* s;
        if (MODE == 0) {
            if (k0 < 256) s = hsb + ((size_t)n*B_TOT + c0 + row0 + arow)*256 + k0 + aseg*16;
            else          s = inputs + ((size_t)n*B_TOT + c0 + row0 + arow)*32 + aseg*16;
        } else {
            s = Asrc + ((size_t)n*Bc + row0 + arow)*256 + k0 + aseg*16;
        }
        u0 = ((const bf16x8*)s)[0];
        u1 = ((const bf16x8*)s)[1];
    };
    auto loadW = [&](int k0, bf16x8 &u0) {
        const unsigned short* s = Wp + ((size_t)n*M + col0 + wrow)*(size_t)KW + k0 + wslot*8;
        u0 = *(const bf16x8*)s;
    };
    auto stage = [&](char* A_, char* W_, bf16x8 a0, bf16x8 a1, bf16x8 w0) {
        *(bf16x8*)(A_ + (aseg*2+0)*AREG + arow*16) = a0;
        *(bf16x8*)(A_ + (aseg*2+1)*AREG + arow*16) = a1;
        *(bf16x8*)(W_ + wslot*WREG + wrow*16) = w0;
    };
    auto compute = [&](char* A_, char* W_) {
        bf16x8 a0 = *(bf16x8*)(A_ + lk*AREG + (w*32 + lr)*16);
        bf16x8 a1 = *(bf16x8*)(A_ + lk*AREG + (w*32 + 16 + lr)*16);
        #pragma unroll
        for (int j = 0; j < NJ; ++j) {
            bf16x8 b = *(bf16x8*)(W_ + lk*WREG + (j*16 + lr)*16);
            acc[0][j] = __builtin_amdgcn_mfma_f32_16x16x32_bf16(a0, b, acc[0][j], 0, 0, 0);
            acc[1][j] = __builtin_amdgcn_mfma_f32_16x16x32_bf16(a1, b, acc[1][j], 0, 0, 0);
        }
    };

    char* AE = (char*)&As[0][0]; char* AO = (char*)&As[1][0];
    char* WE = (char*)&Ws[0][0]; char* WO = (char*)&Ws[1][0];

    loadA(0,  aA0, aA1);  loadW(0,  wA0);
    loadA(32, aB0, aB1);  loadW(32, wB0);

    int tt = 0;
    for (; tt + 1 < NT; tt += 2) {
        stage(AE, WE, aA0, aA1, wA0);
        __syncthreads();
        if (tt + 2 < NT) { loadA((tt+2)*32, aA0, aA1); loadW((tt+2)*32, wA0); }
        compute(AE, WE);

        stage(AO, WO, aB0, aB1, wB0);
        __syncthreads();
        if (tt + 3 < NT) { loadA((tt+3)*32, aB0, aB1); loadW((tt+3)*32, wB0); }
        compute(AO, WO);
    }
    if (tt < NT) {
        stage(AE, WE, aA0, aA1, wA0);
        __syncthreads();
        compute(AE, WE);
    }

    if constexpr (MODE == 0) {
        #pragma unroll
        for (int i = 0; i < 2; ++i) {
            int rbase = row0 + w*32 + i*16 + lk*4;
            #pragma unroll
            for (int half = 0; half < 2; ++half) {
                int o = (col0 >> 2) + half*16 + lr;
                #pragma unroll
                for (int reg = 0; reg < 4; ++reg) {
                    int r = rbase + reg;
                    float rs = acc[i][0+half][reg];
                    float zs = acc[i][2+half][reg];
                    float gx = acc[i][4+half][reg];
                    float gh = acc[i][6+half][reg];
                    float hold = bf2f(hsb[((size_t)n*B_TOT + c0 + r)*256 + o]);
                    float rr = sigm(rs), z = sigm(zs);
                    float nn = tanhf(gx + rr*gh);
                    float h  = nn + z*(hold - nn);
                    hsnb[((size_t)n*Bc + r)*256 + o] = f2bf(h);
                }
            }
        }
    } else {
        #pragma unroll
        for (int i = 0; i < 2; ++i) {
            #pragma unroll
            for (int j = 0; j < NJ; ++j) {
                int c = col0 + j*16 + lr;
                #pragma unroll
                for (int reg = 0; reg < 4; ++reg) {
                    int r = row0 + w*32 + i*16 + lk*4 + reg;
                    float v = acc[i][j][reg];
                    if (c < 64) QKb[((size_t)n*Bc + r)*64 + c] = f2bf(v);
                    else        V2 [((size_t)n*Bc + r)*1024 + (c-64)] = f2fp8(v);
                }
            }
        }
    }
}

// ---------- MODE 2: fp8 x fp8 GEMM, TN=128 (CB=2); masked rows read hsb ----------
__global__ __launch_bounds__(512) void gemm_out_fp8(
    const unsigned char* __restrict__ CTX,   // [n][B][1024] fp8
    const unsigned char* __restrict__ Wo8,   // [n][256][1024] fp8
    const unsigned short* __restrict__ hsnb,
    const unsigned short* __restrict__ hsb,  // masked rows: h_old in bf16 (L3-hot)
    const float* __restrict__ maskf,
    float* __restrict__ outp,
    int Bc, int c0)
{
    constexpr int BM = 256, TN = 128, NJ = 8, NT = 32, CB = 2;
    constexpr int AREG = BM*8;
    constexpr int WREG = TN*8;

    int bid = blockIdx.x;
    int n   = bid & 7;
    int loc = bid >> 3;
    int col0 = (loc % CB) * TN;
    int row0 = (loc / CB) * BM;

    __shared__ unsigned char As[2][BM*32];
    __shared__ unsigned char Ws[2][TN*32];

    int t = threadIdx.x;
    int l = t & 63, w = t >> 6;
    int lr = l & 15, lk = l >> 4;
    int arow = t >> 1, ahalf = t & 1;
    int wrow = t & 127, wslot = t >> 7;

    f32x4 acc[2][NJ];
    #pragma unroll
    for (int i = 0; i < 2; ++i)
        #pragma unroll
        for (int j = 0; j < NJ; ++j)
            acc[i][j] = (f32x4){0.f,0.f,0.f,0.f};

    u64 aA0, aA1, wA0;
    u64 aB0, aB1, wB0;

    auto loadA = [&](int k0, u64 &u0, u64 &u1) {
        const unsigned char* s = CTX + ((size_t)n*Bc + row0 + arow)*1024 + k0 + ahalf*16;
        u0 = *(const u64*)s;
        u1 = *(const u64*)(s + 8);
    };
    auto loadW = [&](int k0, u64 &u0) {
        const unsigned char* s = Wo8 + ((size_t)n*256 + col0 + wrow)*1024 + k0 + wslot*8;
        u0 = *(const u64*)s;
    };
    auto stage = [&](unsigned char* A_, unsigned char* W_, u64 a0, u64 a1, u64 w0) {
        *(u64*)(A_ + (ahalf*2+0)*AREG + arow*8) = a0;
        *(u64*)(A_ + (ahalf*2+1)*AREG + arow*8) = a1;
        *(u64*)(W_ + wslot*WREG + wrow*8) = w0;
    };
    auto compute = [&](unsigned char* A_, unsigned char* W_) {
        long a0 = *(const long*)(A_ + lk*AREG + (w*32 + lr)*8);
        long a1 = *(const long*)(A_ + lk*AREG + (w*32 + 16 + lr)*8);
        #pragma unroll
        for (int j = 0; j < NJ; ++j) {
            long b = *(const long*)(W_ + lk*WREG + (j*16 + lr)*8);
            acc[0][j] = __builtin_amdgcn_mfma_f32_16x16x32_fp8_fp8(a0, b, acc[0][j], 0, 0, 0);
            acc[1][j] = __builtin_amdgcn_mfma_f32_16x16x32_fp8_fp8(a1, b, acc[1][j], 0, 0, 0);
        }
    };

    unsigned char* AE = &As[0][0]; unsigned char* AO = &As[1][0];
    unsigned char* WE = &Ws[0][0]; unsigned char* WO = &Ws[1][0];

    loadA(0,  aA0, aA1);  loadW(0,  wA0);
    loadA(32, aB0, aB1);  loadW(32, wB0);

    for (int tt = 0; tt < NT; tt += 2) {       // NT=32 even
        stage(AE, WE, aA0, aA1, wA0);
        __syncthreads();
        if (tt + 2 < NT) { loadA((tt+2)*32, aA0, aA1); loadW((tt+2)*32, wA0); }
        compute(AE, WE);

        stage(AO, WO, aB0, aB1, wB0);
        __syncthreads();
        if (tt + 3 < NT) { loadA((tt+3)*32, aB0, aB1); loadW((tt+3)*32, wB0); }
        compute(AO, WO);
    }

    #pragma unroll
    for (int i = 0; i < 2; ++i) {
        #pragma unroll
        for (int reg = 0; reg < 4; ++reg) {
            int r = row0 + w*32 + i*16 + lk*4 + reg;
            float mkv = maskf[(size_t)(c0 + r)*8 + n];
            size_t gi0 = (((size_t)(c0 + r))*NU + n)*HH;
            #pragma unroll
            for (int j = 0; j < NJ; ++j) {
                int c = col0 + j*16 + lr;
                float v;
                if (mkv != 0.f) v = acc[i][j][reg] + bf2f(hsnb[((size_t)n*Bc + r)*256 + c]);
                else            v = bf2f(hsb[((size_t)n*B_TOT + c0 + r)*256 + c]);
                outp[gi0 + c] = v;
            }
        }
    }
}

extern "C" void kernel_launch(void* const* d_in, const int* in_sizes, int n_in,
                              void* d_out, int out_size, void* d_ws, size_t ws_size,
                              hipStream_t stream)
{
    const float* x1   = (const float*)d_in[0];
    const float* x2   = (const float*)d_in[1];
    const float* hs   = (const float*)d_in[2];
    const float* Wkey = (const float*)d_in[3];
    const float* bkey = (const float*)d_in[4];
    const float* Wval = (const float*)d_in[5];
    const float* bval = (const float*)d_in[6];
    const float* Wq   = (const float*)d_in[7];
    const float* Wq_  = (const float*)d_in[8];
    const float* Wk_  = (const float*)d_in[9];
    const float* Wv_  = (const float*)d_in[10];
    const float* Wout = (const float*)d_in[11];
    const float* Wx2h = (const float*)d_in[12];
    const float* Wh2h = (const float*)d_in[13];
    float* out = (float*)d_out;

    char* ws = (char*)d_ws;
    size_t off = 0;
    auto alloc = [&](size_t bytes) -> void* {
        void* p = (void*)(ws + off);
        off = (off + bytes + 255) & ~(size_t)255;
        return p;
    };
    unsigned short* Wg     = (unsigned short*)alloc((size_t)8*1024*288*2);
    unsigned short* Wqkv   = (unsigned short*)alloc((size_t)8*1152*256*2);
    unsigned char*  Wo8    = (unsigned char*) alloc((size_t)8*256*1024);
    unsigned short* Wkv    = (unsigned short*)alloc((size_t)48*256*2);
    unsigned short* Wqt    = (unsigned short*)alloc((size_t)8*16*256*2);
    unsigned short* inputs = (unsigned short*)alloc((size_t)8*B_TOT*32*2);
    float*          maskf  = (float*)         alloc((size_t)B_TOT*8*4);
    float*          KV     = (float*)         alloc((size_t)2*B_TOT*48*4);
    float*          qL     = (float*)         alloc((size_t)8*B_TOT*16*4);
    unsigned short* hsb    = (unsigned short*)alloc((size_t)8*B_TOT*256*2);
    size_t persist = off;

    const size_t perB = 8*256*2 + 8*64*2 + 8*1024 + 8*1024;
    int Bc = B_TOT;
    while (Bc > 256 && persist + (size_t)Bc*perB + 65536 > ws_size) Bc >>= 1;
    unsigned short* hsnb = (unsigned short*)alloc((size_t)8*Bc*256*2);
    unsigned short* QKb  = (unsigned short*)alloc((size_t)8*Bc*64*2);
    unsigned char*  V2   = (unsigned char*) alloc((size_t)8*Bc*1024);
    unsigned char*  CTX  = (unsigned char*) alloc((size_t)8*Bc*1024);

    const long long packN = (long long)TG + TQ + TO + TK + TL;
    pack_all<<<(int)((packN + 255)/256), 256, 0, stream>>>(
        Wh2h, Wx2h, Wq_, Wk_, Wv_, Wout, Wkey, Wval, Wq,
        Wg, Wqkv, Wo8, Wkv, Wqt);

    small_gemm<0><<<dim3(2*B_TOT/128), 256, 0, stream>>>(x1, x2, Wkv, KV, nullptr);
    small_gemm<1><<<dim3(B_TOT/128, 8), 256, 0, stream>>>(hs, nullptr, Wqt, qL, hsb);
    score_mask_inputs<<<B_TOT/32, 256, 0, stream>>>(KV, qL, bkey, bval, inputs, maskf);

    for (int c0 = 0; c0 < B_TOT; c0 += Bc) {
        int RB = Bc / 256;
        gemm_mfma<0,128><<<dim3(RB*8*8), 512, 0, stream>>>(
            hsb, inputs, nullptr, Wg, hsnb, nullptr, nullptr, Bc, c0);
        gemm_mfma<1,128><<<dim3(RB*9*8), 512, 0, stream>>>(
            hsb, nullptr, hsnb, Wqkv, nullptr, QKb, V2, Bc, c0);
        attn_kernel<<<Bc/4, 256, 0, stream>>>(QKb, V2, CTX, maskf, Bc, c0);
        gemm_out_fp8<<<dim3(RB*2*8), 512, 0, stream>>>(
            CTX, Wo8, hsnb, hsb, maskf, out, Bc, c0);
    }
}

// Round 19
// 281.873 us; speedup vs baseline: 1.0932x; 1.0552x over previous
//
#include <hip/hip_runtime.h>
#include <math.h>

// BRIMCell forward — bf16 MFMA front GEMMs; fp8(e4m3) v2/ctx stream.
// R19 = R18 + masked-row output moved into M0 epilogue (hold already in reg);
// M2 epilogue active-rows-only (no hsb read, half the out writes).

#define B_TOT 8192
#define NU 8
#define HH 256

typedef __attribute__((ext_vector_type(8))) short bf16x8;
typedef __attribute__((ext_vector_type(4))) float f32x4;
typedef unsigned long long u64;

__device__ __forceinline__ float sigm(float x){ return 1.0f/(1.0f+expf(-x)); }

__device__ __forceinline__ unsigned short f2bf(float f){
    union { float f; unsigned int u; } v; v.f = f;
    unsigned int r = v.u + 0x7fffu + ((v.u >> 16) & 1u);
    return (unsigned short)(r >> 16);
}
__device__ __forceinline__ float bf2f(unsigned short h){
    union { unsigned int u; float f; } v; v.u = ((unsigned int)h) << 16;
    return v.f;
}
__device__ __forceinline__ unsigned char f2fp8(float v){
    int p = __builtin_amdgcn_cvt_pk_fp8_f32(v, v, 0, false);
    return (unsigned char)(p & 0xff);
}

// ---------- fused weight packing ----------
#define TG (8*1024*288)
#define TQ (8*1152*256)
#define TO (8*256*1024)
#define TK (48*256)
#define TL (8*16*256)
__global__ void pack_all(const float* __restrict__ Wh2h, const float* __restrict__ Wx2h,
                         const float* __restrict__ Wq_,  const float* __restrict__ Wk_,
                         const float* __restrict__ Wv_,  const float* __restrict__ Wout,
                         const float* __restrict__ Wkey, const float* __restrict__ Wval,
                         const float* __restrict__ Wq,
                         unsigned short* __restrict__ Wg, unsigned short* __restrict__ Wqkv,
                         unsigned char* __restrict__ Wo8, unsigned short* __restrict__ Wkv,
                         unsigned short* __restrict__ Wqt)
{
    long long gidx = (long long)blockIdx.x*256 + threadIdx.x;
    if (gidx < TG) {
        int idx = (int)gidx;
        int k  = idx % 288;
        int pc = (idx / 288) % 1024;
        int n  = idx / (288*1024);
        int cb = pc >> 7, r = pc & 127;
        int g = r >> 5, ol = r & 31;
        int o = cb*32 + ol;
        float v = 0.f;
        if (g == 0)      v = (k < 256) ? Wh2h[((size_t)n*256 + k)*768 + o]
                                       : Wx2h[((size_t)n*32 + (k-256))*768 + o];
        else if (g == 1) v = (k < 256) ? Wh2h[((size_t)n*256 + k)*768 + 256 + o]
                                       : Wx2h[((size_t)n*32 + (k-256))*768 + 256 + o];
        else if (g == 2) v = (k >= 256) ? Wx2h[((size_t)n*32 + (k-256))*768 + 512 + o] : 0.f;
        else             v = (k < 256) ? Wh2h[((size_t)n*256 + k)*768 + 512 + o] : 0.f;
        Wg[idx] = f2bf(v);
        return;
    }
    gidx -= TG;
    if (gidx < TQ) {
        int idx = (int)gidx;
        int k = idx % 256;
        int c = (idx / 256) % 1152;
        int n = idx / (256*1152);
        float v = 0.f;
        if (c < 32)        v = Wq_[((size_t)n*256+k)*32 + c];
        else if (c < 64)   v = Wk_[((size_t)n*256+k)*32 + (c-32)];
        else if (c < 1088) v = Wv_[((size_t)n*256+k)*1024 + (c-64)];
        Wqkv[idx] = f2bf(v);
        return;
    }
    gidx -= TQ;
    if (gidx < TO) {                 // Wout -> fp8, [n][c(256)][k(1024)]
        int idx = (int)gidx;
        int k = idx % 1024;
        int c = (idx / 1024) % 256;
        int n = idx / (1024*256);
        Wo8[idx] = f2fp8(Wout[((size_t)n*1024 + k)*256 + c]);
        return;
    }
    gidx -= TO;
    if (gidx < TK) {
        int idx = (int)gidx;
        int k = idx & 255, c = idx >> 8;
        float v = (c < 16) ? Wkey[k*16 + c] : Wval[k*32 + (c-16)];
        Wkv[(size_t)c*256 + k] = f2bf(v);
        return;
    }
    gidx -= TK;
    if (gidx < TL) {
        int idx = (int)gidx;
        int k = idx & 255, c = (idx >> 8) & 15, n = idx >> 12;
        Wqt[((size_t)n*16 + c)*256 + k] = f2bf(Wq[((size_t)n*256 + k)*16 + c]);
    }
}

// ---------- small MFMA GEMM for stage-A precursors ----------
template<int SRC>
__global__ __launch_bounds__(256) void small_gemm(
    const float* __restrict__ A0, const float* __restrict__ A1,
    const unsigned short* __restrict__ Wp, float* __restrict__ C,
    unsigned short* __restrict__ hsb)
{
    constexpr int M    = (SRC == 0) ? 48 : 16;
    constexpr int NJ   = M/16;
    constexpr int AREG = 128*16;
    constexpr int WREG = M*16;
    int row0 = blockIdx.x * 128;
    int n = (SRC == 1) ? blockIdx.y : 0;
    const unsigned short* W = Wp + (size_t)n*M*256;

    __shared__ unsigned short As[2][128*32];
    __shared__ unsigned short Ws[2][M*32];

    int t = threadIdx.x, l = t & 63, w = t >> 6;
    int lr = l & 15, lk = l >> 4;
    int arow = t >> 1, aseg = t & 1;

    f32x4 acc[2][NJ];
    #pragma unroll
    for (int i = 0; i < 2; ++i)
        #pragma unroll
        for (int j = 0; j < NJ; ++j)
            acc[i][j] = (f32x4){0.f,0.f,0.f,0.f};

    bf16x8 au0, au1, wu0, wu1;
    auto loadA = [&](int k0, bf16x8 &u0, bf16x8 &u1) {
        const float* src;
        if (SRC == 0) {
            int gr = row0 + arow;
            src = (gr < B_TOT ? A0 + (size_t)gr*HH : A1 + (size_t)(gr - B_TOT)*HH) + k0 + aseg*16;
        } else {
            src = A0 + (((size_t)(row0 + arow))*NU + n)*HH + k0 + aseg*16;
        }
        const float4* s4 = (const float4*)src;
        float4 f0 = s4[0], f1 = s4[1], f2 = s4[2], f3 = s4[3];
        u0[0]=(short)f2bf(f0.x); u0[1]=(short)f2bf(f0.y); u0[2]=(short)f2bf(f0.z); u0[3]=(short)f2bf(f0.w);
        u0[4]=(short)f2bf(f1.x); u0[5]=(short)f2bf(f1.y); u0[6]=(short)f2bf(f1.z); u0[7]=(short)f2bf(f1.w);
        u1[0]=(short)f2bf(f2.x); u1[1]=(short)f2bf(f2.y); u1[2]=(short)f2bf(f2.z); u1[3]=(short)f2bf(f2.w);
        u1[4]=(short)f2bf(f3.x); u1[5]=(short)f2bf(f3.y); u1[6]=(short)f2bf(f3.z); u1[7]=(short)f2bf(f3.w);
        if (SRC == 1) {
            unsigned short* dp = hsb + ((size_t)n*B_TOT + row0 + arow)*256 + k0 + aseg*16;
            *(bf16x8*)dp       = u0;
            *(bf16x8*)(dp + 8) = u1;
        }
    };
    auto loadW = [&](int k0, bf16x8 &u0, bf16x8 &u1) {
        if (t < M*2) {
            const unsigned short* s = W + (size_t)(t >> 1)*256 + k0 + (t & 1)*16;
            u0 = ((const bf16x8*)s)[0];
            u1 = ((const bf16x8*)s)[1];
        }
    };

    loadA(0, au0, au1);
    loadW(0, wu0, wu1);

    for (int tt = 0; tt < 8; ++tt) {
        char* A_ = (char*)&As[tt & 1][0];
        char* W_ = (char*)&Ws[tt & 1][0];
        *(bf16x8*)(A_ + (aseg*2+0)*AREG + arow*16) = au0;
        *(bf16x8*)(A_ + (aseg*2+1)*AREG + arow*16) = au1;
        if (t < M*2) {
            int wrow = t >> 1, wseg = t & 1;
            *(bf16x8*)(W_ + (wseg*2+0)*WREG + wrow*16) = wu0;
            *(bf16x8*)(W_ + (wseg*2+1)*WREG + wrow*16) = wu1;
        }
        __syncthreads();
        if (tt + 1 < 8) {
            loadA((tt+1)*32, au0, au1);
            loadW((tt+1)*32, wu0, wu1);
        }
        bf16x8 a0 = *(bf16x8*)(A_ + lk*AREG + (w*32 + lr)*16);
        bf16x8 a1 = *(bf16x8*)(A_ + lk*AREG + (w*32 + 16 + lr)*16);
        bf16x8 bq[NJ];
        #pragma unroll
        for (int j = 0; j < NJ; ++j)
            bq[j] = *(bf16x8*)(W_ + lk*WREG + (j*16 + lr)*16);
        #pragma unroll
        for (int j = 0; j < NJ; ++j) {
            acc[0][j] = __builtin_amdgcn_mfma_f32_16x16x32_bf16(a0, bq[j], acc[0][j], 0, 0, 0);
            acc[1][j] = __builtin_amdgcn_mfma_f32_16x16x32_bf16(a1, bq[j], acc[1][j], 0, 0, 0);
        }
    }

    float* Cb = (SRC == 0) ? C : C + (size_t)n*B_TOT*16;
    #pragma unroll
    for (int i = 0; i < 2; ++i)
        #pragma unroll
        for (int j = 0; j < NJ; ++j)
            #pragma unroll
            for (int reg = 0; reg < 4; ++reg) {
                int r = row0 + w*32 + i*16 + lk*4 + reg;
                Cb[(size_t)r*M + j*16 + lr] = acc[i][j][reg];
            }
}

// ---------- scores -> softmax -> mask -> inputs ----------
__global__ __launch_bounds__(256) void score_mask_inputs(
    const float* __restrict__ KV,
    const float* __restrict__ qL,
    const float* __restrict__ bkey, const float* __restrict__ bval,
    unsigned short* __restrict__ inputs, float* __restrict__ maskf)
{
    int t  = threadIdx.x;
    int gb = blockIdx.x*32 + (t >> 3);
    int n  = t & 7, l = t & 63;

    float q[16];
    const float* qp = qL + ((size_t)n*B_TOT + gb)*16;
    #pragma unroll
    for (int i = 0; i < 4; ++i) *(float4*)&q[i*4] = ((const float4*)qp)[i];

    const float* kv0 = KV + (size_t)gb*48;
    const float* kv1 = KV + (size_t)(B_TOT + gb)*48;

    float s0 = 0.f, s1 = 0.f, sn = 0.f;
    #pragma unroll
    for (int k = 0; k < 16; ++k) {
        float bk = bkey[k];
        s0 += q[k]*(kv0[k] + bk);
        s1 += q[k]*(kv1[k] + bk);
        sn += q[k]*bk;
    }
    s0 *= 0.25f; s1 *= 0.25f; sn *= 0.25f;

    float mx = fmaxf(s0, fmaxf(s1, sn));
    float e0 = expf(s0-mx), e1 = expf(s1-mx), en = expf(sn-mx);
    float inv = 1.f/(e0+e1+en);
    float p0 = e0*inv, p1 = e1*inv, pn = en*inv;

    int rank = 0;
    #pragma unroll
    for (int m = 0; m < 8; ++m) {
        float sm = __shfl(sn, (l & ~7) + m, 64);
        if (sm > sn || (sm == sn && m < n)) rank++;
    }
    float mk = (rank < 4) ? 0.f : 1.f;
    maskf[(size_t)gb*8 + n] = mk;

    unsigned short* op = inputs + ((size_t)n*B_TOT + gb)*32;
    #pragma unroll
    for (int db = 0; db < 4; ++db) {
        bf16x8 o;
        #pragma unroll
        for (int e = 0; e < 8; ++e) {
            int d = db*8 + e;
            float bv = bval[d];
            float v = mk*(p0*(kv0[16+d]+bv) + p1*(kv1[16+d]+bv) + pn*bv);
            o[e] = (short)f2bf(v);
        }
        *(bf16x8*)&op[db*8] = o;
    }
}

// ---------- attention: q2k2 bf16 in, v2 fp8 in, ctx fp8 out (active n only) ----------
__global__ __launch_bounds__(256) void attn_kernel(
    const unsigned short* __restrict__ QKb,   // [n][B][64] bf16
    const unsigned char*  __restrict__ V2,    // [n][B][1024] fp8
    unsigned char* __restrict__ CTX,          // [n][B][1024] fp8
    const float* __restrict__ maskf, int Bc, int c0)
{
    int wid = threadIdx.x >> 6;
    int l   = threadIdx.x & 63;
    int b   = blockIdx.x*4 + wid;
    int gb  = c0 + b;

    __shared__ float qk[4][8][64];
    __shared__ float P[4][4][8][8];
    __shared__ float mk[4][8];

    for (int it = 0; it < 8; ++it) {
        int idx = l + 64*it;
        int n = idx >> 6, c = idx & 63;
        qk[wid][n][c] = bf2f(QKb[((size_t)n*Bc + b)*64 + c]);
    }
    if (l < 8) mk[wid][l] = maskf[(size_t)gb*8 + l];
    __syncthreads();

    for (int it = 0; it < 4; ++it) {
        int idx = l + 64*it;
        int h = idx >> 6, n = (idx >> 3) & 7, m = idx & 7;
        float s = 0.f;
        #pragma unroll
        for (int dk = 0; dk < 8; ++dk) s += qk[wid][n][h*8 + dk]*qk[wid][m][32 + h*8 + dk];
        P[wid][h][n][m] = s * 0.35355339059327373f;
    }
    __syncthreads();

    if (l < 32) {
        int h = l >> 3, n = l & 7;
        float mx = -1e30f;
        for (int m = 0; m < 8; ++m) mx = fmaxf(mx, P[wid][h][n][m]);
        float e[8], sum = 0.f;
        for (int m = 0; m < 8; ++m) { e[m] = expf(P[wid][h][n][m]-mx); sum += e[m]; }
        float scl = mk[wid][n] / sum;
        for (int m = 0; m < 8; ++m) P[wid][h][n][m] = e[m]*scl;
    }
    __syncthreads();

    #pragma unroll
    for (int it = 0; it < 2; ++it) {
        int colb = (l + 64*it)*8;
        int h = colb >> 8;
        float acc[8][8];
        #pragma unroll
        for (int n = 0; n < 8; ++n)
            #pragma unroll
            for (int c = 0; c < 8; ++c) acc[n][c] = 0.f;
        for (int m = 0; m < 8; ++m) {
            uint2 v8 = *(const uint2*)&V2[((size_t)m*Bc + b)*1024 + colb];
            float vf[8];
            vf[0] = __builtin_amdgcn_cvt_f32_fp8(v8.x, 0);
            vf[1] = __builtin_amdgcn_cvt_f32_fp8(v8.x, 1);
            vf[2] = __builtin_amdgcn_cvt_f32_fp8(v8.x, 2);
            vf[3] = __builtin_amdgcn_cvt_f32_fp8(v8.x, 3);
            vf[4] = __builtin_amdgcn_cvt_f32_fp8(v8.y, 0);
            vf[5] = __builtin_amdgcn_cvt_f32_fp8(v8.y, 1);
            vf[6] = __builtin_amdgcn_cvt_f32_fp8(v8.y, 2);
            vf[7] = __builtin_amdgcn_cvt_f32_fp8(v8.y, 3);
            #pragma unroll
            for (int n = 0; n < 8; ++n) {
                float p = P[wid][h][n][m];
                #pragma unroll
                for (int c = 0; c < 8; ++c) acc[n][c] += p*vf[c];
            }
        }
        #pragma unroll
        for (int n = 0; n < 8; ++n) {
            if (mk[wid][n] != 0.f) {
                int lo = __builtin_amdgcn_cvt_pk_fp8_f32(acc[n][0], acc[n][1], 0,  false);
                lo     = __builtin_amdgcn_cvt_pk_fp8_f32(acc[n][2], acc[n][3], lo, true);
                int hi = __builtin_amdgcn_cvt_pk_fp8_f32(acc[n][4], acc[n][5], 0,  false);
                hi     = __builtin_amdgcn_cvt_pk_fp8_f32(acc[n][6], acc[n][7], hi, true);
                uint2 o; o.x = (unsigned int)lo; o.y = (unsigned int)hi;
                *(uint2*)&CTX[((size_t)n*Bc + b)*1024 + colb] = o;
            }
        }
    }
}

// ---------- bf16 MFMA GEMM (MODE 0: gates+GRU+masked-out; MODE 1: qkv) ----------
template<int MODE, int TN>
__global__ __launch_bounds__(512) void gemm_mfma(
    const unsigned short* __restrict__ hsb,
    const unsigned short* __restrict__ inputs,
    const unsigned short* __restrict__ Asrc,
    const unsigned short* __restrict__ Wp,
    unsigned short* __restrict__ hsnb,
    unsigned short* __restrict__ QKb,
    unsigned char*  __restrict__ V2,
    const float* __restrict__ maskf,
    float* __restrict__ outp,
    int Bc, int c0)
{
    constexpr int KW   = (MODE==0) ? 288 : 256;
    constexpr int M    = (MODE==0) ? 1024 : 1152;
    constexpr int BM   = 256;
    constexpr int NJ   = TN/16;
    constexpr int NT   = KW/32;
    constexpr int CB   = M/TN;
    constexpr int AREG = BM*16;
    constexpr int WREG = TN*16;

    int bid = blockIdx.x;
    int n   = bid & 7;
    int loc = bid >> 3;
    int col0 = (loc % CB) * TN;
    int row0 = (loc / CB) * BM;

    __shared__ unsigned short As[2][BM*32];
    __shared__ unsigned short Ws[2][TN*32];

    int t = threadIdx.x;
    int l = t & 63, w = t >> 6;
    int lr = l & 15, lk = l >> 4;

    int arow = t >> 1, aseg = t & 1;
    int wrow = t & 127, wslot = t >> 7;

    f32x4 acc[2][NJ];
    #pragma unroll
    for (int i = 0; i < 2; ++i)
        #pragma unroll
        for (int j = 0; j < NJ; ++j)
            acc[i][j] = (f32x4){0.f,0.f,0.f,0.f};

    bf16x8 aA0, aA1, wA0;
    bf16x8 aB0, aB1, wB0;

    auto loadA = [&](int k0, bf16x8 &u0, bf16x8 &u1) {
        const unsigned short* s;
        if (MODE == 0) {
            if (k0 < 256) s = hsb + ((size_t)n*B_TOT + c0 + row0 + arow)*256 + k0 + aseg*16;
            else          s = inputs + ((size_t)n*B_TOT + c0 + row0 + arow)*32 + aseg*16;
        } else {
            s = Asrc + ((size_t)n*Bc + row0 + arow)*256 + k0 + aseg*16;
        }
        u0 = ((const bf16x8*)s)[0];
        u1 = ((const bf16x8*)s)[1];
    };
    auto loadW = [&](int k0, bf16x8 &u0) {
        const unsigned short* s = Wp + ((size_t)n*M + col0 + wrow)*(size_t)KW + k0 + wslot*8;
        u0 = *(const bf16x8*)s;
    };
    auto stage = [&](char* A_, char* W_, bf16x8 a0, bf16x8 a1, bf16x8 w0) {
        *(bf16x8*)(A_ + (aseg*2+0)*AREG + arow*16) = a0;
        *(bf16x8*)(A_ + (aseg*2+1)*AREG + arow*16) = a1;
        *(bf16x8*)(W_ + wslot*WREG + wrow*16) = w0;
    };
    auto compute = [&](char* A_, char* W_) {
        bf16x8 a0 = *(bf16x8*)(A_ + lk*AREG + (w*32 + lr)*16);
        bf16x8 a1 = *(bf16x8*)(A_ + lk*AREG + (w*32 + 16 + lr)*16);
        #pragma unroll
        for (int j = 0; j < NJ; ++j) {
            bf16x8 b = *(bf16x8*)(W_ + lk*WREG + (j*16 + lr)*16);
            acc[0][j] = __builtin_amdgcn_mfma_f32_16x16x32_bf16(a0, b, acc[0][j], 0, 0, 0);
            acc[1][j] = __builtin_amdgcn_mfma_f32_16x16x32_bf16(a1, b, acc[1][j], 0, 0, 0);
        }
    };

    char* AE = (char*)&As[0][0]; char* AO = (char*)&As[1][0];
    char* WE = (char*)&Ws[0][0]; char* WO = (char*)&Ws[1][0];

    loadA(0,  aA0, aA1);  loadW(0,  wA0);
    loadA(32, aB0, aB1);  loadW(32, wB0);

    int tt = 0;
    for (; tt + 1 < NT; tt += 2) {
        stage(AE, WE, aA0, aA1, wA0);
        __syncthreads();
        if (tt + 2 < NT) { loadA((tt+2)*32, aA0, aA1); loadW((tt+2)*32, wA0); }
        compute(AE, WE);

        stage(AO, WO, aB0, aB1, wB0);
        __syncthreads();
        if (tt + 3 < NT) { loadA((tt+3)*32, aB0, aB1); loadW((tt+3)*32, wB0); }
        compute(AO, WO);
    }
    if (tt < NT) {
        stage(AE, WE, aA0, aA1, wA0);
        __syncthreads();
        compute(AE, WE);
    }

    if constexpr (MODE == 0) {
        #pragma unroll
        for (int i = 0; i < 2; ++i) {
            int rbase = row0 + w*32 + i*16 + lk*4;
            #pragma unroll
            for (int half = 0; half < 2; ++half) {
                int o = (col0 >> 2) + half*16 + lr;
                #pragma unroll
                for (int reg = 0; reg < 4; ++reg) {
                    int r = rbase + reg;
                    float rs = acc[i][0+half][reg];
                    float zs = acc[i][2+half][reg];
                    float gx = acc[i][4+half][reg];
                    float gh = acc[i][6+half][reg];
                    float hold = bf2f(hsb[((size_t)n*B_TOT + c0 + r)*256 + o]);
                    float rr = sigm(rs), z = sigm(zs);
                    float nn = tanhf(gx + rr*gh);
                    float h  = nn + z*(hold - nn);
                    hsnb[((size_t)n*Bc + r)*256 + o] = f2bf(h);
                    // masked rows: final output is h_old — write it HERE
                    // (hold already in register; M2 then skips masked rows)
                    if (maskf[(size_t)(c0 + r)*8 + n] == 0.f)
                        outp[(((size_t)(c0 + r))*NU + n)*HH + o] = hold;
                }
            }
        }
    } else {
        #pragma unroll
        for (int i = 0; i < 2; ++i) {
            #pragma unroll
            for (int j = 0; j < NJ; ++j) {
                int c = col0 + j*16 + lr;
                #pragma unroll
                for (int reg = 0; reg < 4; ++reg) {
                    int r = row0 + w*32 + i*16 + lk*4 + reg;
                    float v = acc[i][j][reg];
                    if (c < 64) QKb[((size_t)n*Bc + r)*64 + c] = f2bf(v);
                    else        V2 [((size_t)n*Bc + r)*1024 + (c-64)] = f2fp8(v);
                }
            }
        }
    }
}

// ---------- MODE 2: fp8 x fp8 GEMM, TN=128 (CB=2); active rows only ----------
__global__ __launch_bounds__(512) void gemm_out_fp8(
    const unsigned char* __restrict__ CTX,   // [n][B][1024] fp8
    const unsigned char* __restrict__ Wo8,   // [n][256][1024] fp8
    const unsigned short* __restrict__ hsnb,
    const float* __restrict__ maskf,
    float* __restrict__ outp,
    int Bc, int c0)
{
    constexpr int BM = 256, TN = 128, NJ = 8, NT = 32, CB = 2;
    constexpr int AREG = BM*8;
    constexpr int WREG = TN*8;

    int bid = blockIdx.x;
    int n   = bid & 7;
    int loc = bid >> 3;
    int col0 = (loc % CB) * TN;
    int row0 = (loc / CB) * BM;

    __shared__ unsigned char As[2][BM*32];
    __shared__ unsigned char Ws[2][TN*32];

    int t = threadIdx.x;
    int l = t & 63, w = t >> 6;
    int lr = l & 15, lk = l >> 4;
    int arow = t >> 1, ahalf = t & 1;
    int wrow = t & 127, wslot = t >> 7;

    f32x4 acc[2][NJ];
    #pragma unroll
    for (int i = 0; i < 2; ++i)
        #pragma unroll
        for (int j = 0; j < NJ; ++j)
            acc[i][j] = (f32x4){0.f,0.f,0.f,0.f};

    u64 aA0, aA1, wA0;
    u64 aB0, aB1, wB0;

    auto loadA = [&](int k0, u64 &u0, u64 &u1) {
        const unsigned char* s = CTX + ((size_t)n*Bc + row0 + arow)*1024 + k0 + ahalf*16;
        u0 = *(const u64*)s;
        u1 = *(const u64*)(s + 8);
    };
    auto loadW = [&](int k0, u64 &u0) {
        const unsigned char* s = Wo8 + ((size_t)n*256 + col0 + wrow)*1024 + k0 + wslot*8;
        u0 = *(const u64*)s;
    };
    auto stage = [&](unsigned char* A_, unsigned char* W_, u64 a0, u64 a1, u64 w0) {
        *(u64*)(A_ + (ahalf*2+0)*AREG + arow*8) = a0;
        *(u64*)(A_ + (ahalf*2+1)*AREG + arow*8) = a1;
        *(u64*)(W_ + wslot*WREG + wrow*8) = w0;
    };
    auto compute = [&](unsigned char* A_, unsigned char* W_) {
        long a0 = *(const long*)(A_ + lk*AREG + (w*32 + lr)*8);
        long a1 = *(const long*)(A_ + lk*AREG + (w*32 + 16 + lr)*8);
        #pragma unroll
        for (int j = 0; j < NJ; ++j) {
            long b = *(const long*)(W_ + lk*WREG + (j*16 + lr)*8);
            acc[0][j] = __builtin_amdgcn_mfma_f32_16x16x32_fp8_fp8(a0, b, acc[0][j], 0, 0, 0);
            acc[1][j] = __builtin_amdgcn_mfma_f32_16x16x32_fp8_fp8(a1, b, acc[1][j], 0, 0, 0);
        }
    };

    unsigned char* AE = &As[0][0]; unsigned char* AO = &As[1][0];
    unsigned char* WE = &Ws[0][0]; unsigned char* WO = &Ws[1][0];

    loadA(0,  aA0, aA1);  loadW(0,  wA0);
    loadA(32, aB0, aB1);  loadW(32, wB0);

    for (int tt = 0; tt < NT; tt += 2) {       // NT=32 even
        stage(AE, WE, aA0, aA1, wA0);
        __syncthreads();
        if (tt + 2 < NT) { loadA((tt+2)*32, aA0, aA1); loadW((tt+2)*32, wA0); }
        compute(AE, WE);

        stage(AO, WO, aB0, aB1, wB0);
        __syncthreads();
        if (tt + 3 < NT) { loadA((tt+3)*32, aB0, aB1); loadW((tt+3)*32, wB0); }
        compute(AO, WO);
    }

    #pragma unroll
    for (int i = 0; i < 2; ++i) {
        #pragma unroll
        for (int reg = 0; reg < 4; ++reg) {
            int r = row0 + w*32 + i*16 + lk*4 + reg;
            float mkv = maskf[(size_t)(c0 + r)*8 + n];
            if (mkv != 0.f) {                  // masked rows written by M0
                size_t gi0 = (((size_t)(c0 + r))*NU + n)*HH;
                #pragma unroll
                for (int j = 0; j < NJ; ++j) {
                    int c = col0 + j*16 + lr;
                    outp[gi0 + c] = acc[i][j][reg] + bf2f(hsnb[((size_t)n*Bc + r)*256 + c]);
                }
            }
        }
    }
}

extern "C" void kernel_launch(void* const* d_in, const int* in_sizes, int n_in,
                              void* d_out, int out_size, void* d_ws, size_t ws_size,
                              hipStream_t stream)
{
    const float* x1   = (const float*)d_in[0];
    const float* x2   = (const float*)d_in[1];
    const float* hs   = (const float*)d_in[2];
    const float* Wkey = (const float*)d_in[3];
    const float* bkey = (const float*)d_in[4];
    const float* Wval = (const float*)d_in[5];
    const float* bval = (const float*)d_in[6];
    const float* Wq   = (const float*)d_in[7];
    const float* Wq_  = (const float*)d_in[8];
    const float* Wk_  = (const float*)d_in[9];
    const float* Wv_  = (const float*)d_in[10];
    const float* Wout = (const float*)d_in[11];
    const float* Wx2h = (const float*)d_in[12];
    const float* Wh2h = (const float*)d_in[13];
    float* out = (float*)d_out;

    char* ws = (char*)d_ws;
    size_t off = 0;
    auto alloc = [&](size_t bytes) -> void* {
        void* p = (void*)(ws + off);
        off = (off + bytes + 255) & ~(size_t)255;
        return p;
    };
    unsigned short* Wg     = (unsigned short*)alloc((size_t)8*1024*288*2);
    unsigned short* Wqkv   = (unsigned short*)alloc((size_t)8*1152*256*2);
    unsigned char*  Wo8    = (unsigned char*) alloc((size_t)8*256*1024);
    unsigned short* Wkv    = (unsigned short*)alloc((size_t)48*256*2);
    unsigned short* Wqt    = (unsigned short*)alloc((size_t)8*16*256*2);
    unsigned short* inputs = (unsigned short*)alloc((size_t)8*B_TOT*32*2);
    float*          maskf  = (float*)         alloc((size_t)B_TOT*8*4);
    float*          KV     = (float*)         alloc((size_t)2*B_TOT*48*4);
    float*          qL     = (float*)         alloc((size_t)8*B_TOT*16*4);
    unsigned short* hsb    = (unsigned short*)alloc((size_t)8*B_TOT*256*2);
    size_t persist = off;

    const size_t perB = 8*256*2 + 8*64*2 + 8*1024 + 8*1024;
    int Bc = B_TOT;
    while (Bc > 256 && persist + (size_t)Bc*perB + 65536 > ws_size) Bc >>= 1;
    unsigned short* hsnb = (unsigned short*)alloc((size_t)8*Bc*256*2);
    unsigned short* QKb  = (unsigned short*)alloc((size_t)8*Bc*64*2);
    unsigned char*  V2   = (unsigned char*) alloc((size_t)8*Bc*1024);
    unsigned char*  CTX  = (unsigned char*) alloc((size_t)8*Bc*1024);

    const long long packN = (long long)TG + TQ + TO + TK + TL;
    pack_all<<<(int)((packN + 255)/256), 256, 0, stream>>>(
        Wh2h, Wx2h, Wq_, Wk_, Wv_, Wout, Wkey, Wval, Wq,
        Wg, Wqkv, Wo8, Wkv, Wqt);

    small_gemm<0><<<dim3(2*B_TOT/128), 256, 0, stream>>>(x1, x2, Wkv, KV, nullptr);
    small_gemm<1><<<dim3(B_TOT/128, 8), 256, 0, stream>>>(hs, nullptr, Wqt, qL, hsb);
    score_mask_inputs<<<B_TOT/32, 256, 0, stream>>>(KV, qL, bkey, bval, inputs, maskf);

    for (int c0 = 0; c0 < B_TOT; c0 += Bc) {
        int RB = Bc / 256;
        gemm_mfma<0,128><<<dim3(RB*8*8), 512, 0, stream>>>(
            hsb, inputs, nullptr, Wg, hsnb, nullptr, nullptr, maskf, out, Bc, c0);
        gemm_mfma<1,128><<<dim3(RB*9*8), 512, 0, stream>>>(
            hsb, nullptr, hsnb, Wqkv, nullptr, QKb, V2, maskf, out, Bc, c0);
        attn_kernel<<<Bc/4, 256, 0, stream>>>(QKb, V2, CTX, maskf, Bc, c0);
        gemm_out_fp8<<<dim3(RB*2*8), 512, 0, stream>>>(
            CTX, Wo8, hsnb, maskf, out, Bc, c0);
    }
}